// Round 14
// baseline (71.394 us; speedup 1.0000x reference)
//
#include <hip/hip_runtime.h>
#include <math.h>

// probs/targets: (32,1,512,512) fp32
// ROUND 14 = DIAGNOSTIC #2 (production path = r9, best 19.14us, untouched).
// diagA: full-compute hot loop x8 at FULL occupancy -> VALUBusy disambiguates
//        VALU-throughput-bound (hidden inst bloat, r10's 19.6%@2w/SIMD => ~80%@8)
//        vs memory-service-bound (~40%).
// diagB: minimal probe body x8 at scale -> does 13.7 TB/s survive repetition?
// Decision tree pre-committed in journal.
#define NS 32
#define NELEM 262144
#define PBLK 16               // production: partial blocks per sample
#define GRID (NS * PBLK)      // 512 blocks
#define TPB 256
#define CHUNK (NELEM / PBLK)  // 16384 elem/block; 64/thread

#define NPART (NS * PBLK)     // 512 partial sets (production)
#define OFF_S1   0
#define OFF_S2   (NPART * 1)
#define OFF_DOT  (NPART * 2)
#define OFF_MX   (NPART * 3)
#define OFF_CGT  (NPART * 4)
#define OFF_PK   (NPART * 5)
// diag area: floats [4096..12288), ints [12288..16384) — 64KB total (<= proven ws)
#define NDIAG 2048
#define OFF_DF  4096
#define OFF_DI  12288

__device__ __forceinline__ void comb(float& mx, int& pk, float m2, int pk2) {
    const bool g = m2 > mx;
    const bool e = m2 == mx;
    pk = g ? pk2 : (pk + (e ? pk2 : 0));
    mx = fmaxf(mx, m2);
}

struct Acc {
    float4 a1, a2, ad;
    int cgt;
    float mx;
    int pk;
};

__device__ __forceinline__ void consume(Acc& A, const float4 (&pv)[4],
                                        const float4 (&tv)[4]) {
#pragma unroll
    for (int k = 0; k < 4; ++k) {
        A.a1.x += pv[k].x; A.a1.y += pv[k].y; A.a1.z += pv[k].z; A.a1.w += pv[k].w;
        A.a2.x += tv[k].x; A.a2.y += tv[k].y; A.a2.z += tv[k].z; A.a2.w += tv[k].w;
        A.ad.x = fmaf(pv[k].x, tv[k].x, A.ad.x);
        A.ad.y = fmaf(pv[k].y, tv[k].y, A.ad.y);
        A.ad.z = fmaf(pv[k].z, tv[k].z, A.ad.z);
        A.ad.w = fmaf(pv[k].w, tv[k].w, A.ad.w);
    }
    const float mX = fmaxf(fmaxf(tv[0].x, tv[1].x), fmaxf(tv[2].x, tv[3].x));
    const float mY = fmaxf(fmaxf(tv[0].y, tv[1].y), fmaxf(tv[2].y, tv[3].y));
    const float mZ = fmaxf(fmaxf(tv[0].z, tv[1].z), fmaxf(tv[2].z, tv[3].z));
    const float mW = fmaxf(fmaxf(tv[0].w, tv[1].w), fmaxf(tv[2].w, tv[3].w));
    const float mg = fmaxf(fmaxf(mX, mY), fmaxf(mZ, mW));
    int cp = 0, cg = 0, gg = 0;
#pragma unroll
    for (int k = 0; k < 4; ++k) {
        const float pc[4] = {pv[k].x, pv[k].y, pv[k].z, pv[k].w};
        const float tc[4] = {tv[k].x, tv[k].y, tv[k].z, tv[k].w};
#pragma unroll
        for (int j = 0; j < 4; ++j) {
            const int b1 = pc[j] > 0.5f;
            const int eq = tc[j] == mg;
            cp += b1;
            cg += eq;
            gg += eq & b1;
        }
    }
    A.cgt += cp;
    comb(A.mx, A.pk, mg, (cg << 16) | gg);
}

// ---------------- production k_partial (r9, unchanged) ----------------
__global__ __launch_bounds__(TPB) void k_partial(const float* __restrict__ probs,
                                                 const float* __restrict__ tgts,
                                                 float* __restrict__ wsf,
                                                 int* __restrict__ wsi) {
    const int b = blockIdx.x;
    const int s = b >> 4;
    const int c = b & (PBLK - 1);
    const size_t base = (size_t)s * NELEM + (size_t)c * CHUNK;
    const float4* __restrict__ p4 = (const float4*)(probs + base);
    const float4* __restrict__ t4 = (const float4*)(tgts + base);
    const int t = threadIdx.x;

    Acc A;
    A.a1 = {0.f,0.f,0.f,0.f}; A.a2 = {0.f,0.f,0.f,0.f}; A.ad = {0.f,0.f,0.f,0.f};
    A.cgt = 0; A.mx = -INFINITY; A.pk = 0;

    float4 pA[4], tA[4], pB[4], tB[4];
#pragma unroll
    for (int k = 0; k < 4; ++k) { pA[k] = p4[k*256 + t];        tA[k] = t4[k*256 + t]; }
#pragma unroll
    for (int k = 0; k < 4; ++k) { pB[k] = p4[1024 + k*256 + t]; tB[k] = t4[1024 + k*256 + t]; }
    consume(A, pA, tA);
#pragma unroll
    for (int k = 0; k < 4; ++k) { pA[k] = p4[2048 + k*256 + t]; tA[k] = t4[2048 + k*256 + t]; }
    consume(A, pB, tB);
#pragma unroll
    for (int k = 0; k < 4; ++k) { pB[k] = p4[3072 + k*256 + t]; tB[k] = t4[3072 + k*256 + t]; }
    consume(A, pA, tA);
    consume(A, pB, tB);

    float s1 = (A.a1.x + A.a1.y) + (A.a1.z + A.a1.w);
    float s2 = (A.a2.x + A.a2.y) + (A.a2.z + A.a2.w);
    float dt = (A.ad.x + A.ad.y) + (A.ad.z + A.ad.w);
    int cgt = A.cgt;
    float mxr = A.mx;
    int pkr = A.pk;

#pragma unroll
    for (int off = 32; off; off >>= 1) {
        s1  += __shfl_xor(s1, off);
        s2  += __shfl_xor(s2, off);
        dt  += __shfl_xor(dt, off);
        cgt += __shfl_xor(cgt, off);
        const float m2 = __shfl_xor(mxr, off);
        const int  pk2 = __shfl_xor(pkr, off);
        comb(mxr, pkr, m2, pk2);
    }

    __shared__ float ls1[4], ls2[4], ldt[4], lmx[4];
    __shared__ int   lcg[4], lpk[4];
    const int w = t >> 6, lane = t & 63;
    if (lane == 0) {
        ls1[w] = s1; ls2[w] = s2; ldt[w] = dt; lmx[w] = mxr;
        lcg[w] = cgt; lpk[w] = pkr;
    }
    __syncthreads();
    if (t == 0) {
#pragma unroll
        for (int w2 = 1; w2 < TPB / 64; ++w2) {
            s1 += ls1[w2]; s2 += ls2[w2]; dt += ldt[w2]; cgt += lcg[w2];
            comb(mxr, pkr, lmx[w2], lpk[w2]);
        }
        wsf[OFF_S1  + b] = s1;
        wsf[OFF_S2  + b] = s2;
        wsf[OFF_DOT + b] = dt;
        wsf[OFF_MX  + b] = mxr;
        wsi[OFF_CGT + b] = cgt;
        wsi[OFF_PK  + b] = pkr;
    }
}

// ---------------- diagA: full compute, full occupancy, x8 reps ----------------
__global__ __launch_bounds__(TPB, 8) void k_diagA(const float* __restrict__ probs,
                                                  const float* __restrict__ tgts,
                                                  float* __restrict__ wsf,
                                                  int* __restrict__ wsi) {
    const int b = blockIdx.x;           // 2048 blocks: 64 chunks/sample of 4096
    const int s = b >> 6;
    const int c = b & 63;
    const int t = threadIdx.x;

    Acc A;
    A.a1 = {0.f,0.f,0.f,0.f}; A.a2 = {0.f,0.f,0.f,0.f}; A.ad = {0.f,0.f,0.f,0.f};
    A.cgt = 0; A.mx = -INFINITY; A.pk = 0;

#pragma unroll 1
    for (int rep = 0; rep < 8; ++rep) {
        const int c2 = (c + rep * 8) & 63;
        const size_t base = (size_t)s * NELEM + (size_t)c2 * 4096;
        const float4* __restrict__ p4 = (const float4*)(probs + base);
        const float4* __restrict__ t4 = (const float4*)(tgts + base);
        float4 pv[4], tv[4];
#pragma unroll
        for (int k = 0; k < 4; ++k) {
            pv[k] = p4[k * 256 + t];
            tv[k] = t4[k * 256 + t];
        }
        consume(A, pv, tv);
    }

    // lean block store (per-thread fold -> wave store via shfl at end)
    float s1 = (A.a1.x + A.a1.y) + (A.a1.z + A.a1.w);
    float s2 = (A.a2.x + A.a2.y) + (A.a2.z + A.a2.w);
    float dt = (A.ad.x + A.ad.y) + (A.ad.z + A.ad.w);
    int cgt = A.cgt;
    float mxr = A.mx;
    int pkr = A.pk;
#pragma unroll
    for (int off = 32; off; off >>= 1) {
        s1  += __shfl_xor(s1, off);
        s2  += __shfl_xor(s2, off);
        dt  += __shfl_xor(dt, off);
        cgt += __shfl_xor(cgt, off);
        const float m2 = __shfl_xor(mxr, off);
        const int  pk2 = __shfl_xor(pkr, off);
        comb(mxr, pkr, m2, pk2);
    }
    if (t == 0) {   // one set per block is enough to keep everything live
        wsf[OFF_DF + 0 * NDIAG + b] = s1;
        wsf[OFF_DF + 1 * NDIAG + b] = s2;
        wsf[OFF_DF + 2 * NDIAG + b] = dt;
        wsf[OFF_DF + 3 * NDIAG + b] = mxr;
        wsi[OFF_DI + 0 * NDIAG + b] = cgt;
        wsi[OFF_DI + 1 * NDIAG + b] = pkr;
    }
}

// ---------------- diagB: minimal probe body, x8 reps at scale ----------------
__global__ __launch_bounds__(TPB, 8) void k_diagB(const float* __restrict__ probs,
                                                  const float* __restrict__ tgts,
                                                  float* __restrict__ sink) {
    const int b = blockIdx.x;
    const int s = b >> 6;
    const int c = b & 63;
    const int t = threadIdx.x;

    float4 ap = {0.f,0.f,0.f,0.f}, at = {0.f,0.f,0.f,0.f};
#pragma unroll 1
    for (int rep = 0; rep < 8; ++rep) {
        const int c2 = (c + rep * 8) & 63;
        const size_t base = (size_t)s * NELEM + (size_t)c2 * 4096;
        const float4* __restrict__ p4 = (const float4*)(probs + base);
        const float4* __restrict__ t4 = (const float4*)(tgts + base);
        float4 pv[4], tv[4];
#pragma unroll
        for (int k = 0; k < 4; ++k) {
            pv[k] = p4[k * 256 + t];
            tv[k] = t4[k * 256 + t];
        }
#pragma unroll
        for (int k = 0; k < 4; ++k) {
            ap.x += pv[k].x; ap.y += pv[k].y; ap.z += pv[k].z; ap.w += pv[k].w;
            at.x += tv[k].x; at.y += tv[k].y; at.z += tv[k].z; at.w += tv[k].w;
        }
    }
    float v = (ap.x + ap.y) + (ap.z + ap.w) + (at.x + at.y) + (at.z + at.w);
    if (t == 0) sink[b] = v;   // overwrites diagA area AFTER diagA (serialized)
}

__device__ __forceinline__ void combine_max(float& mx, int& cnt, int& gt,
                                            float mx2, int cnt2, int gt2) {
    if (mx2 > mx) { mx = mx2; cnt = cnt2; gt = gt2; }
    else if (mx2 == mx) { cnt += cnt2; gt += gt2; }
}

// production finalize (r9, unchanged)
__global__ __launch_bounds__(512) void k_final(const float* __restrict__ wsf,
                                               const int* __restrict__ wsi,
                                               float* __restrict__ out) {
    __shared__ float scores[NS];
    const int t = threadIdx.x;
    const int w = t >> 6, lane = t & 63;
    const int samp = (w << 2) + (lane >> 4);
    const int pidx = lane & 15;
    const int idx = samp * PBLK + pidx;

    float s1  = wsf[OFF_S1  + idx];
    float s2  = wsf[OFF_S2  + idx];
    float dot = wsf[OFF_DOT + idx];
    float mx  = wsf[OFF_MX  + idx];
    int   cgt = wsi[OFF_CGT + idx];
    const int pk = wsi[OFF_PK + idx];
    int   cnt = pk >> 16;
    int   gt  = pk & 0xFFFF;

#pragma unroll
    for (int off = 8; off; off >>= 1) {
        s1  += __shfl_xor(s1, off);
        s2  += __shfl_xor(s2, off);
        dot += __shfl_xor(dot, off);
        cgt += __shfl_xor(cgt, off);
        float m2 = __shfl_xor(mx, off);
        int   c2 = __shfl_xor(cnt, off);
        int   g2 = __shfl_xor(gt, off);
        combine_max(mx, cnt, gt, m2, c2, g2);
    }

    if (pidx == 0) {
        const int cle = NELEM - cgt;
        const long long corr = (long long)cle - (long long)cnt + 2LL * (long long)gt;
        float score = 2.0f * (dot + 1.0f) / (s1 + s2 + 1.0f);
        if (corr == 1) score = 1.0f;   // acc == 1.0 (probs.shape[1] == 1)
        scores[samp] = 1.0f - score;
    }

    __syncthreads();
    if (t < 64) {
        float v = (t < NS) ? scores[t] : 0.0f;
#pragma unroll
        for (int off = 32; off; off >>= 1) v += __shfl_xor(v, off);
        if (t == 0) out[0] = v * (1.0f / (float)NS);
    }
}

extern "C" void kernel_launch(void* const* d_in, const int* in_sizes, int n_in,
                              void* d_out, int out_size, void* d_ws, size_t ws_size,
                              hipStream_t stream) {
    const float* probs = (const float*)d_in[0];
    const float* tgts  = (const float*)d_in[1];
    float* wsf = (float*)d_ws;
    int*   wsi = (int*)d_ws;
    float* out = (float*)d_out;

    k_partial<<<GRID, TPB, 0, stream>>>(probs, tgts, wsf, wsi);
    k_diagA<<<2048, TPB, 0, stream>>>(probs, tgts, wsf, wsi);    // diagnostic
    k_diagB<<<2048, TPB, 0, stream>>>(probs, tgts, wsf + OFF_DF); // diagnostic
    k_final<<<1, 512, 0, stream>>>(wsf, wsi, out);
}

// Round 15
// 22.346 us; speedup vs baseline: 3.1949x; 3.1949x over previous
//
#include <hip/hip_runtime.h>
#include <math.h>

// probs/targets: (32,1,512,512) fp32
// ROUND 15: minimum-code-footprint k_partial at best geometry (512 blocks).
// r14 pinned the gap as per-dispatch ramp that scales with code size (cold
// I-fetch): warm full-compute reps run ~4us/pass; single-shot big kernels pay
// 8.6-12. Rolled loop (~60-instr body) + DPP/permlane reduce (no LDS, no
// syncthreads, no ds_bpermute) + per-wave stores. Counting stays per-lane
// VALU (r8/r13: SALU counting loses — 1 scalar unit vs 4 SIMDs).
#define NS 32
#define NELEM 262144
#define TPB 256
#define GRID 512              // 16 blocks/sample
#define CHUNK (NELEM / 16)    // 16384 elem/block; 64/thread
#define NSETS 2048            // one set per wave (512 blk x 4 waves); 64/sample

__device__ __forceinline__ unsigned f2u(float x) { return __builtin_bit_cast(unsigned, x); }
__device__ __forceinline__ float u2f(unsigned x) { return __builtin_bit_cast(float, x); }

// (mx, pk=(cnt<<16)|gt) semigroup: replace on greater, add on equal
__device__ __forceinline__ void comb(float& mx, int& pk, float m2, int pk2) {
    const bool g = m2 > mx;
    const bool e = m2 == mx;
    pk = g ? pk2 : (pk + (e ? pk2 : 0));
    mx = fmaxf(mx, m2);
}

template<int CTRL>
__device__ __forceinline__ float dppf(float v) {
    return u2f((unsigned)__builtin_amdgcn_update_dpp((int)f2u(v), (int)f2u(v),
                                                     CTRL, 0xF, 0xF, false));
}
template<int CTRL>
__device__ __forceinline__ int dppi(int v) {
    return __builtin_amdgcn_update_dpp(v, v, CTRL, 0xF, 0xF, false);
}

template<int N>
__device__ __forceinline__ void level_ror(float& s1, float& s2, float& dt,
                                          int& cgt, float& mx, int& pk) {
    s1 += dppf<0x120 + N>(s1);
    s2 += dppf<0x120 + N>(s2);
    dt += dppf<0x120 + N>(dt);
    cgt += dppi<0x120 + N>(cgt);
    const float m2 = dppf<0x120 + N>(mx);
    const int   p2 = dppi<0x120 + N>(pk);
    comb(mx, pk, m2, p2);
}

#if __has_builtin(__builtin_amdgcn_permlane16_swap) && __has_builtin(__builtin_amdgcn_permlane32_swap)
template<bool WIDE>
__device__ __forceinline__ void level_swap(float& s1, float& s2, float& dt,
                                           int& cgt, float& mx, int& pk) {
#define SWAP_(x) (WIDE ? __builtin_amdgcn_permlane32_swap((x), (x), false, false) \
                       : __builtin_amdgcn_permlane16_swap((x), (x), false, false))
    { auto r = SWAP_(f2u(s1)); s1 = u2f(r[0]) + u2f(r[1]); }
    { auto r = SWAP_(f2u(s2)); s2 = u2f(r[0]) + u2f(r[1]); }
    { auto r = SWAP_(f2u(dt)); dt = u2f(r[0]) + u2f(r[1]); }
    { auto r = SWAP_((unsigned)cgt); cgt = (int)(r[0] + r[1]); }
    { auto rm = SWAP_(f2u(mx));
      auto rp = SWAP_((unsigned)pk);
      float mA = u2f(rm[0]); int pA = (int)rp[0];
      comb(mA, pA, u2f(rm[1]), (int)rp[1]);
      mx = mA; pk = pA; }
#undef SWAP_
}
#else
template<bool WIDE>
__device__ __forceinline__ void level_swap(float& s1, float& s2, float& dt,
                                           int& cgt, float& mx, int& pk) {
    const int off = WIDE ? 32 : 16;
    s1 += __shfl_xor(s1, off);
    s2 += __shfl_xor(s2, off);
    dt += __shfl_xor(dt, off);
    cgt += __shfl_xor(cgt, off);
    const float m2 = __shfl_xor(mx, off);
    const int   p2 = __shfl_xor(pk, off);
    comb(mx, pk, m2, p2);
}
#endif

// ws layout: floats s1|s2|dt|mx at [0..4)*NSETS; ints cgt|pk at [4..6)*NSETS
__global__ __launch_bounds__(TPB) void k_partial(const float* __restrict__ probs,
                                                 const float* __restrict__ tgts,
                                                 float* __restrict__ wsf,
                                                 int* __restrict__ wsi) {
    const int b = blockIdx.x;
    const int s = b >> 4;           // sample
    const int c = b & 15;           // chunk within sample
    const size_t base = (size_t)s * NELEM + (size_t)c * CHUNK;
    const float4* __restrict__ p4 = (const float4*)(probs + base);
    const float4* __restrict__ t4 = (const float4*)(tgts + base);
    const int t = threadIdx.x;

    float4 a1 = {0.f,0.f,0.f,0.f}, a2 = {0.f,0.f,0.f,0.f}, ad = {0.f,0.f,0.f,0.f};
    int cgt = 0, pk = 0;
    float mx = -INFINITY;

    // ROLLED loop: 4 iterations x 16 elem/thread — small I-footprint
#pragma unroll 1
    for (int g = 0; g < 4; ++g) {
        float4 pv[4], tv[4];
#pragma unroll
        for (int k = 0; k < 4; ++k) {
            pv[k] = p4[g * 1024 + k * 256 + t];
            tv[k] = t4[g * 1024 + k * 256 + t];
        }
        // component-parallel sums
#pragma unroll
        for (int k = 0; k < 4; ++k) {
            a1.x += pv[k].x; a1.y += pv[k].y; a1.z += pv[k].z; a1.w += pv[k].w;
            a2.x += tv[k].x; a2.y += tv[k].y; a2.z += tv[k].z; a2.w += tv[k].w;
            ad.x = fmaf(pv[k].x, tv[k].x, ad.x);
            ad.y = fmaf(pv[k].y, tv[k].y, ad.y);
            ad.z = fmaf(pv[k].z, tv[k].z, ad.z);
            ad.w = fmaf(pv[k].w, tv[k].w, ad.w);
        }
        // group max via pairwise tree (depth 4)
        const float mX = fmaxf(fmaxf(tv[0].x, tv[1].x), fmaxf(tv[2].x, tv[3].x));
        const float mY = fmaxf(fmaxf(tv[0].y, tv[1].y), fmaxf(tv[2].y, tv[3].y));
        const float mZ = fmaxf(fmaxf(tv[0].z, tv[1].z), fmaxf(tv[2].z, tv[3].z));
        const float mW = fmaxf(fmaxf(tv[0].w, tv[1].w), fmaxf(tv[2].w, tv[3].w));
        const float mg = fmaxf(fmaxf(mX, mY), fmaxf(mZ, mW));
        // branch-free recount vs group max (per-lane VALU — proven cheapest)
        int cp = 0, cg = 0, gg = 0;
#pragma unroll
        for (int k = 0; k < 4; ++k) {
            const float pc[4] = {pv[k].x, pv[k].y, pv[k].z, pv[k].w};
            const float tc[4] = {tv[k].x, tv[k].y, tv[k].z, tv[k].w};
#pragma unroll
            for (int j = 0; j < 4; ++j) {
                const int b1 = pc[j] > 0.5f;
                const int eq = tc[j] == mg;
                cp += b1;
                cg += eq;
                gg += eq & b1;
            }
        }
        cgt += cp;
        comb(mx, pk, mg, (cg << 16) | gg);
    }

    float s1 = (a1.x + a1.y) + (a1.z + a1.w);
    float s2 = (a2.x + a2.y) + (a2.z + a2.w);
    float dt = (ad.x + ad.y) + (ad.z + ad.w);

    // full 64-lane reduce on the VALU pipe (no LDS, no barrier, no DS ops)
    level_ror<8>(s1, s2, dt, cgt, mx, pk);
    level_ror<4>(s1, s2, dt, cgt, mx, pk);
    level_ror<2>(s1, s2, dt, cgt, mx, pk);
    level_ror<1>(s1, s2, dt, cgt, mx, pk);
    level_swap<false>(s1, s2, dt, cgt, mx, pk);   // lane^16
    level_swap<true >(s1, s2, dt, cgt, mx, pk);   // lane^32

    if ((t & 63) == 0) {
        const int g = b * (TPB / 64) + (t >> 6);  // one set per wave
        wsf[0 * NSETS + g] = s1;                  // sets for sample s are
        wsf[1 * NSETS + g] = s2;                  // contiguous: [s*64,(s+1)*64)
        wsf[2 * NSETS + g] = dt;
        wsf[3 * NSETS + g] = mx;
        wsi[4 * NSETS + g] = cgt;
        wsi[5 * NSETS + g] = pk;                  // wave counts <= 4096
    }
}

__device__ __forceinline__ void combine_max(float& mx, int& cnt, int& gt,
                                            float mx2, int cnt2, int gt2) {
    if (mx2 > mx) { mx = mx2; cnt = cnt2; gt = gt2; }
    else if (mx2 == mx) { cnt += cnt2; gt += gt2; }
}

// finalize + mean: 1 block x 1024 threads; wave w reduces samples 2w, 2w+1
// (64 sets each, one per lane). Unpack pk first (sample counts > 16 bits).
__global__ __launch_bounds__(1024) void k_final(const float* __restrict__ wsf,
                                                const int* __restrict__ wsi,
                                                float* __restrict__ out) {
    __shared__ float scores[NS];
    const int t = threadIdx.x;
    const int w = t >> 6, lane = t & 63;

#pragma unroll
    for (int r = 0; r < 2; ++r) {
        const int samp = w * 2 + r;
        const int idx = samp * 64 + lane;

        float s1  = wsf[0 * NSETS + idx];
        float s2  = wsf[1 * NSETS + idx];
        float dot = wsf[2 * NSETS + idx];
        float mx  = wsf[3 * NSETS + idx];
        int   cgt = wsi[4 * NSETS + idx];
        const int pk = wsi[5 * NSETS + idx];
        int   cnt = pk >> 16;
        int   gt  = pk & 0xFFFF;

#pragma unroll
        for (int off = 32; off; off >>= 1) {
            s1  += __shfl_xor(s1, off);
            s2  += __shfl_xor(s2, off);
            dot += __shfl_xor(dot, off);
            cgt += __shfl_xor(cgt, off);
            float m2 = __shfl_xor(mx, off);
            int   c2 = __shfl_xor(cnt, off);
            int   g2 = __shfl_xor(gt, off);
            combine_max(mx, cnt, gt, m2, c2, g2);
        }

        if (lane == 0) {
            const int cle = NELEM - cgt;   // count(p <= 0.5)
            const long long corr = (long long)cle - (long long)cnt + 2LL * (long long)gt;
            float score = 2.0f * (dot + 1.0f) / (s1 + s2 + 1.0f);
            if (corr == 1) score = 1.0f;   // acc == 1.0 (probs.shape[1] == 1)
            scores[samp] = 1.0f - score;
        }
    }

    __syncthreads();
    if (t < 64) {
        float v = (t < NS) ? scores[t] : 0.0f;
#pragma unroll
        for (int off = 32; off; off >>= 1) v += __shfl_xor(v, off);
        if (t == 0) out[0] = v * (1.0f / (float)NS);
    }
}

extern "C" void kernel_launch(void* const* d_in, const int* in_sizes, int n_in,
                              void* d_out, int out_size, void* d_ws, size_t ws_size,
                              hipStream_t stream) {
    const float* probs = (const float*)d_in[0];
    const float* tgts  = (const float*)d_in[1];
    float* wsf = (float*)d_ws;
    int*   wsi = (int*)d_ws;
    float* out = (float*)d_out;

    k_partial<<<GRID, TPB, 0, stream>>>(probs, tgts, wsf, wsi);
    k_final<<<1, 1024, 0, stream>>>(wsf, wsi, out);
}

// Round 16
// 19.258 us; speedup vs baseline: 3.7073x; 1.1604x over previous
//
#include <hip/hip_runtime.h>
#include <math.h>

// probs/targets: (32,1,512,512) fp32
// FINAL (revert to r9 = best measured, 19.14us). Structure: 512 blocks x
// 256 thr x 64 elem/thread, register double-buffer streaming, branch-free
// two-pass max counting, 6-quantity shuffle butterfly, LDS cross-wave merge,
// fused finalize+mean (1 block).
// Ceiling decomposition (r4/r5/r10/r14 calibrations): ~9.1us fixed replay
// overhead + ~8.5us k_partial (incl ~3.6us per-dispatch ramp; warm floor
// ~4.9us L3-resident) + ~1.5us finalize. Seven structural rewrites
// (r6,r7,r8,r11,r12,r13,r15) all landed 19.1-22.7 => structural ceiling.
#define NS 32
#define NELEM 262144
#define PBLK 16               // partial blocks per sample
#define GRID (NS * PBLK)      // 512 blocks
#define TPB 256               // 4 waves
#define CHUNK (NELEM / PBLK)  // 16384 elements per block; 64 per thread

#define NPART (NS * PBLK)     // 512 partial sets
#define OFF_S1   0
#define OFF_S2   (NPART * 1)
#define OFF_DOT  (NPART * 2)
#define OFF_MX   (NPART * 3)
#define OFF_CGT  (NPART * 4)  // int: count(p > 0.5)
#define OFF_PK   (NPART * 5)  // int: (cnt_at_max << 16) | gt_at_max

// branch-free (mx,pk) semigroup combine; 16-bit fields hold block-scope counts
__device__ __forceinline__ void comb(float& mx, int& pk, float m2, int pk2) {
    const bool g = m2 > mx;
    const bool e = m2 == mx;
    pk = g ? pk2 : (pk + (e ? pk2 : 0));
    mx = fmaxf(mx, m2);
}

struct Acc {
    float4 a1, a2, ad;
    int cgt;
    float mx;
    int pk;
};

__device__ __forceinline__ void consume(Acc& A, const float4 (&pv)[4],
                                        const float4 (&tv)[4]) {
    // sums — component-parallel, no scalar chains
#pragma unroll
    for (int k = 0; k < 4; ++k) {
        A.a1.x += pv[k].x; A.a1.y += pv[k].y; A.a1.z += pv[k].z; A.a1.w += pv[k].w;
        A.a2.x += tv[k].x; A.a2.y += tv[k].y; A.a2.z += tv[k].z; A.a2.w += tv[k].w;
        A.ad.x = fmaf(pv[k].x, tv[k].x, A.ad.x);
        A.ad.y = fmaf(pv[k].y, tv[k].y, A.ad.y);
        A.ad.z = fmaf(pv[k].z, tv[k].z, A.ad.z);
        A.ad.w = fmaf(pv[k].w, tv[k].w, A.ad.w);
    }
    // group max via pairwise tree (depth 4)
    const float mX = fmaxf(fmaxf(tv[0].x, tv[1].x), fmaxf(tv[2].x, tv[3].x));
    const float mY = fmaxf(fmaxf(tv[0].y, tv[1].y), fmaxf(tv[2].y, tv[3].y));
    const float mZ = fmaxf(fmaxf(tv[0].z, tv[1].z), fmaxf(tv[2].z, tv[3].z));
    const float mW = fmaxf(fmaxf(tv[0].w, tv[1].w), fmaxf(tv[2].w, tv[3].w));
    const float mg = fmaxf(fmaxf(mX, mY), fmaxf(mZ, mW));
    // branch-free recount vs group max
    int cp = 0, cg = 0, gg = 0;
#pragma unroll
    for (int k = 0; k < 4; ++k) {
        const float pc[4] = {pv[k].x, pv[k].y, pv[k].z, pv[k].w};
        const float tc[4] = {tv[k].x, tv[k].y, tv[k].z, tv[k].w};
#pragma unroll
        for (int j = 0; j < 4; ++j) {
            const int b1 = pc[j] > 0.5f;
            const int eq = tc[j] == mg;
            cp += b1;
            cg += eq;
            gg += eq & b1;
        }
    }
    A.cgt += cp;
    comb(A.mx, A.pk, mg, (cg << 16) | gg);
}

__global__ __launch_bounds__(TPB) void k_partial(const float* __restrict__ probs,
                                                 const float* __restrict__ tgts,
                                                 float* __restrict__ wsf,
                                                 int* __restrict__ wsi) {
    const int b = blockIdx.x;
    const int s = b >> 4;           // sample
    const int c = b & (PBLK - 1);   // chunk within sample
    const size_t base = (size_t)s * NELEM + (size_t)c * CHUNK;
    const float4* __restrict__ p4 = (const float4*)(probs + base);
    const float4* __restrict__ t4 = (const float4*)(tgts + base);
    const int t = threadIdx.x;

    Acc A;
    A.a1 = {0.f,0.f,0.f,0.f}; A.a2 = {0.f,0.f,0.f,0.f}; A.ad = {0.f,0.f,0.f,0.f};
    A.cgt = 0; A.mx = -INFINITY; A.pk = 0;

    // register double-buffer: issue next group's loads before computing current
    float4 pA[4], tA[4], pB[4], tB[4];

#pragma unroll
    for (int k = 0; k < 4; ++k) { pA[k] = p4[0*1024 + k*256 + t]; tA[k] = t4[0*1024 + k*256 + t]; }
#pragma unroll
    for (int k = 0; k < 4; ++k) { pB[k] = p4[1*1024 + k*256 + t]; tB[k] = t4[1*1024 + k*256 + t]; }
    consume(A, pA, tA);                      // G0 (while G1 in flight)
#pragma unroll
    for (int k = 0; k < 4; ++k) { pA[k] = p4[2*1024 + k*256 + t]; tA[k] = t4[2*1024 + k*256 + t]; }
    consume(A, pB, tB);                      // G1 (while G2 in flight)
#pragma unroll
    for (int k = 0; k < 4; ++k) { pB[k] = p4[3*1024 + k*256 + t]; tB[k] = t4[3*1024 + k*256 + t]; }
    consume(A, pA, tA);                      // G2 (while G3 in flight)
    consume(A, pB, tB);                      // G3

    float s1 = (A.a1.x + A.a1.y) + (A.a1.z + A.a1.w);
    float s2 = (A.a2.x + A.a2.y) + (A.a2.z + A.a2.w);
    float dt = (A.ad.x + A.ad.y) + (A.ad.z + A.ad.w);
    int cgt = A.cgt;
    float mxr = A.mx;
    int pkr = A.pk;

    // wave butterfly: 6 quantities x 6 levels
#pragma unroll
    for (int off = 32; off; off >>= 1) {
        s1  += __shfl_xor(s1, off);
        s2  += __shfl_xor(s2, off);
        dt  += __shfl_xor(dt, off);
        cgt += __shfl_xor(cgt, off);
        const float m2 = __shfl_xor(mxr, off);
        const int  pk2 = __shfl_xor(pkr, off);
        comb(mxr, pkr, m2, pk2);
    }

    // cross-wave via LDS (4 waves)
    __shared__ float ls1[4], ls2[4], ldt[4], lmx[4];
    __shared__ int   lcg[4], lpk[4];
    const int w = t >> 6, lane = t & 63;
    if (lane == 0) {
        ls1[w] = s1; ls2[w] = s2; ldt[w] = dt; lmx[w] = mxr;
        lcg[w] = cgt; lpk[w] = pkr;
    }
    __syncthreads();
    if (t == 0) {
#pragma unroll
        for (int w2 = 1; w2 < TPB / 64; ++w2) {
            s1 += ls1[w2]; s2 += ls2[w2]; dt += ldt[w2]; cgt += lcg[w2];
            comb(mxr, pkr, lmx[w2], lpk[w2]);
        }
        wsf[OFF_S1  + b] = s1;
        wsf[OFF_S2  + b] = s2;
        wsf[OFF_DOT + b] = dt;
        wsf[OFF_MX  + b] = mxr;
        wsi[OFF_CGT + b] = cgt;
        wsi[OFF_PK  + b] = pkr;
    }
}

__device__ __forceinline__ void combine_max(float& mx, int& cnt, int& gt,
                                            float mx2, int cnt2, int gt2) {
    if (mx2 > mx) { mx = mx2; cnt = cnt2; gt = gt2; }
    else if (mx2 == mx) { cnt += cnt2; gt += gt2; }
}

// finalize + mean: 512 threads (8 waves); each 16-lane group reduces one
// sample's 16 partials (segmented butterfly, offsets 8/4/2/1)
__global__ __launch_bounds__(512) void k_final(const float* __restrict__ wsf,
                                               const int* __restrict__ wsi,
                                               float* __restrict__ out) {
    __shared__ float scores[NS];
    const int t = threadIdx.x;
    const int w = t >> 6, lane = t & 63;
    const int samp = (w << 2) + (lane >> 4);  // 8 waves x 4 samples
    const int pidx = lane & 15;
    const int idx = samp * PBLK + pidx;

    float s1  = wsf[OFF_S1  + idx];
    float s2  = wsf[OFF_S2  + idx];
    float dot = wsf[OFF_DOT + idx];
    float mx  = wsf[OFF_MX  + idx];
    int   cgt = wsi[OFF_CGT + idx];
    const int pk = wsi[OFF_PK + idx];
    int   cnt = pk >> 16;      // unpack: sample-level counts exceed 16 bits
    int   gt  = pk & 0xFFFF;

#pragma unroll
    for (int off = 8; off; off >>= 1) {      // stays within 16-lane group
        s1  += __shfl_xor(s1, off);
        s2  += __shfl_xor(s2, off);
        dot += __shfl_xor(dot, off);
        cgt += __shfl_xor(cgt, off);
        float m2 = __shfl_xor(mx, off);
        int   c2 = __shfl_xor(cnt, off);
        int   g2 = __shfl_xor(gt, off);
        combine_max(mx, cnt, gt, m2, c2, g2);
    }

    if (pidx == 0) {
        const int cle = NELEM - cgt;         // count(p <= 0.5)
        const long long corr = (long long)cle - (long long)cnt + 2LL * (long long)gt;
        float score = 2.0f * (dot + 1.0f) / (s1 + s2 + 1.0f);
        if (corr == 1) score = 1.0f;         // acc == 1.0 (probs.shape[1] == 1)
        scores[samp] = 1.0f - score;
    }

    __syncthreads();
    if (t < 64) {
        float v = (t < NS) ? scores[t] : 0.0f;
#pragma unroll
        for (int off = 32; off; off >>= 1) v += __shfl_xor(v, off);
        if (t == 0) out[0] = v * (1.0f / (float)NS);
    }
}

extern "C" void kernel_launch(void* const* d_in, const int* in_sizes, int n_in,
                              void* d_out, int out_size, void* d_ws, size_t ws_size,
                              hipStream_t stream) {
    const float* probs = (const float*)d_in[0];
    const float* tgts  = (const float*)d_in[1];
    float* wsf = (float*)d_ws;
    int*   wsi = (int*)d_ws;
    float* out = (float*)d_out;

    k_partial<<<GRID, TPB, 0, stream>>>(probs, tgts, wsf, wsi);
    k_final<<<1, 512, 0, stream>>>(wsf, wsi, out);
}